// Round 5
// baseline (258.450 us; speedup 1.0000x reference)
//
#include <hip/hip_runtime.h>
#include <math.h>

typedef float f32x4 __attribute__((ext_vector_type(4)));
typedef unsigned int u32x4 __attribute__((ext_vector_type(4)));
typedef short bf16x8 __attribute__((ext_vector_type(8)));

__device__ __forceinline__ unsigned f2bf1(float f) {
  unsigned u = __builtin_bit_cast(unsigned, f);
  return (u + 0x7FFFu + ((u >> 16) & 1u)) >> 16;
}
__device__ __forceinline__ unsigned pack2(float a, float b) {
  return f2bf1(a) | (f2bf1(b) << 16);
}

__device__ __forceinline__ f32x4 mfma16(u32x4 a, u32x4 b, f32x4 c) {
  return __builtin_amdgcn_mfma_f32_16x16x32_bf16(
      __builtin_bit_cast(bf16x8, a), __builtin_bit_cast(bf16x8, b), c, 0, 0, 0);
}

// Convert C/D accumulators of Z^T into A/B-layout bf16 fragments of Z.
// Input acc[s_tile][f_tile]: element r = Z^T[s_tile*16 + 4g + r][f_tile*16 + f]
// Output frag[f_tile][ks]: bf16 element j = Z[f_tile*16 + f][ks*32 + g*8 + j]
template <int NS, int NF, int NKS>
__device__ __forceinline__ void cvt_frags(const f32x4 (&acc)[NS][NF],
                                          u32x4 (&frag)[NF][NKS],
                                          int f, int g) {
  unsigned pk[NS][NF][2];
#pragma unroll
  for (int s = 0; s < NS; ++s)
#pragma unroll
    for (int n = 0; n < NF; ++n) {
      pk[s][n][0] = pack2(acc[s][n][0], acc[s][n][1]);
      pk[s][n][1] = pack2(acc[s][n][2], acc[s][n][3]);
    }
  const bool hi = ((g >> 1) & 1) != 0;
#pragma unroll
  for (int w = 0; w < 4; ++w) {
    const int gp = 2 * (g & 1) + (w >> 1);
    const int idx = (f + (gp << 4)) << 2;
#pragma unroll
    for (int n = 0; n < NF; ++n)
#pragma unroll
      for (int ks = 0; ks < NKS; ++ks) {
        int lo = __builtin_amdgcn_ds_bpermute(idx, (int)pk[2 * ks + 0][n][w & 1]);
        int h2 = __builtin_amdgcn_ds_bpermute(idx, (int)pk[2 * ks + 1][n][w & 1]);
        frag[n][ks][w] = (unsigned)(hi ? h2 : lo);
      }
  }
}

__launch_bounds__(256, 2)
__global__ void lwmh_kernel(const float* __restrict__ x,
                            const float* __restrict__ Wq,
                            const float* __restrict__ Wk,
                            const float* __restrict__ Wv,
                            float* __restrict__ out,
                            float* __restrict__ attw,
                            int nb) {
  const int lane = threadIdx.x & 63;
  const int f = lane & 15;
  const int g = lane >> 4;
  const int wid = blockIdx.x * (blockDim.x >> 6) + (threadIdx.x >> 6);
  const int nwaves = gridDim.x * (blockDim.x >> 6);

  // ---- once-per-wave precompute ----
  u32x4 aWq[4][2], bWkT[4][2];
#pragma unroll
  for (int ct = 0; ct < 4; ++ct)
#pragma unroll
    for (int hs = 0; hs < 2; ++hs) {
      const int off = (ct * 16 + f) * 64 + hs * 32 + g * 8;
      f32x4 ql = *(const f32x4*)(Wq + off);
      f32x4 qh = *(const f32x4*)(Wq + off + 4);
      f32x4 kl = *(const f32x4*)(Wk + off);
      f32x4 kh = *(const f32x4*)(Wk + off + 4);
      u32x4 fq, fk;
      fq[0] = pack2(ql[0], ql[1]); fq[1] = pack2(ql[2], ql[3]);
      fq[2] = pack2(qh[0], qh[1]); fq[3] = pack2(qh[2], qh[3]);
      fk[0] = pack2(kl[0], kl[1]); fk[1] = pack2(kl[2], kl[3]);
      fk[2] = pack2(kh[0], kh[1]); fk[3] = pack2(kh[2], kh[3]);
      aWq[ct][hs] = fq;
      bWkT[ct][hs] = fk;
    }

  u32x4 wv[4][2];
#pragma unroll
  for (int t = 0; t < 4; ++t)
#pragma unroll
    for (int ks = 0; ks < 2; ++ks) {
      const float* bv = Wv + (ks * 32 + g * 8) * 64 + t * 16 + f;
      u32x4 fv;
#pragma unroll
      for (int w = 0; w < 4; ++w)
        fv[w] = pack2(bv[(2 * w) * 64], bv[(2 * w + 1) * 64]);
      wv[t][ks] = fv;
    }

  // N = Wk Wq^T / 8 as A-frags.
  u32x4 aN[4][2];
#pragma unroll
  for (int nc = 0; nc < 4; ++nc) {
    f32x4 nacc[4][1];
#pragma unroll
    for (int mc = 0; mc < 4; ++mc) {
      f32x4 a = {0.f, 0.f, 0.f, 0.f};
#pragma unroll
      for (int hs = 0; hs < 2; ++hs) a = mfma16(aWq[mc][hs], bWkT[nc][hs], a);
      nacc[mc][0] = a * 0.125f;
    }
    u32x4 tmp[1][2];
    cvt_frags<4, 1, 2>(nacc, tmp, f, g);
    aN[nc][0] = tmp[0][0];
    aN[nc][1] = tmp[0][1];
  }

  // ---- main loop, repeated 2x (DIAGNOSTIC: surface kernel in rocprof top-5;
  // identical idempotent work each rep, deterministic) ----
  f32x4 xc[2][2][2], xn[2][2][2];

  auto loadX = [&](int b, f32x4 (&xr)[2][2][2]) {
    const float* xb = x + (size_t)b * 2048;
#pragma unroll
    for (int mt = 0; mt < 2; ++mt)
#pragma unroll
      for (int ks = 0; ks < 2; ++ks) {
        const float* p0 = xb + (mt * 16 + f) * 64 + ks * 32 + g * 8;
        xr[mt][ks][0] = *(const f32x4*)p0;
        xr[mt][ks][1] = *(const f32x4*)(p0 + 4);
      }
  };

  for (int rep = 0; rep < 2; ++rep) {
    int b = wid;
    if (b < nb) loadX(b, xc);

    for (; b < nb; b += nwaves) {
      const int bn = b + nwaves;
      if (bn < nb) loadX(bn, xn);  // prefetch next block

      u32x4 xf[2][2];
#pragma unroll
      for (int mt = 0; mt < 2; ++mt)
#pragma unroll
        for (int ks = 0; ks < 2; ++ks) {
          u32x4 fr;
          fr[0] = pack2(xc[mt][ks][0][0], xc[mt][ks][0][1]);
          fr[1] = pack2(xc[mt][ks][0][2], xc[mt][ks][0][3]);
          fr[2] = pack2(xc[mt][ks][1][0], xc[mt][ks][1][1]);
          fr[3] = pack2(xc[mt][ks][1][2], xc[mt][ks][1][3]);
          xf[mt][ks] = fr;
        }

      // T2 = N @ X^T
      f32x4 t2[4][2];
#pragma unroll
      for (int mc = 0; mc < 4; ++mc)
#pragma unroll
        for (int nt = 0; nt < 2; ++nt) {
          f32x4 a = {0.f, 0.f, 0.f, 0.f};
#pragma unroll
          for (int ks = 0; ks < 2; ++ks) a = mfma16(aN[mc][ks], xf[nt][ks], a);
          t2[mc][nt] = a;
        }
      u32x4 bT2[2][2];
      cvt_frags<4, 2, 2>(t2, bT2, f, g);

      // V = X @ Wv
      f32x4 va[2][4];
#pragma unroll
      for (int ms = 0; ms < 2; ++ms)
#pragma unroll
        for (int nh = 0; nh < 4; ++nh) {
          f32x4 a = {0.f, 0.f, 0.f, 0.f};
#pragma unroll
          for (int ks = 0; ks < 2; ++ks) a = mfma16(xf[ms][ks], wv[nh][ks], a);
          va[ms][nh] = a;
        }
      u32x4 bV[4][1];
      cvt_frags<2, 4, 1>(va, bV, f, g);

      // S^T = X @ T2
      f32x4 st[2][2];
#pragma unroll
      for (int ms = 0; ms < 2; ++ms)
#pragma unroll
        for (int nt = 0; nt < 2; ++nt) {
          f32x4 a = {0.f, 0.f, 0.f, 0.f};
#pragma unroll
          for (int ks = 0; ks < 2; ++ks) a = mfma16(xf[ms][ks], bT2[nt][ks], a);
          st[ms][nt] = a;
        }

      // masked softmax over s
      f32x4 pe[2][2];
#pragma unroll
      for (int nt = 0; nt < 2; ++nt) {
        const int t = nt * 16 + f;
        float sum = 0.f;
#pragma unroll
        for (int ms = 0; ms < 2; ++ms)
#pragma unroll
          for (int r = 0; r < 4; ++r) {
            const int s = ms * 16 + 4 * g + r;
            const float e =
                ((unsigned)(t - s) <= 7u) ? __expf(st[ms][nt][r]) : 0.f;
            pe[ms][nt][r] = e;
            sum += e;
          }
        sum += __shfl_xor(sum, 16);
        sum += __shfl_xor(sum, 32);
        const float inv = 1.0f / sum;
#pragma unroll
        for (int ms = 0; ms < 2; ++ms)
          pe[ms][nt] *= inv;
      }

      // attention weights
      {
        float* aw = attw + (size_t)b * 1024;
#pragma unroll
        for (int ms = 0; ms < 2; ++ms)
#pragma unroll
          for (int nt = 0; nt < 2; ++nt)
            *(f32x4*)(aw + (nt * 16 + f) * 32 + ms * 16 + 4 * g) = pe[ms][nt];
      }

      // P -> bf16 A-frags
      u32x4 aP[2][1];
      cvt_frags<2, 2, 1>(pe, aP, f, g);

      // O = P @ V
      f32x4 o[2][4];
#pragma unroll
      for (int mt = 0; mt < 2; ++mt)
#pragma unroll
        for (int nh = 0; nh < 4; ++nh) {
          f32x4 a = {0.f, 0.f, 0.f, 0.f};
          o[mt][nh] = mfma16(aP[mt][0], bV[nh][0], a);
        }

      {
        float* op = out + (size_t)b * 2048;
#pragma unroll
        for (int mt = 0; mt < 2; ++mt)
#pragma unroll
          for (int nh = 0; nh < 4; ++nh)
#pragma unroll
            for (int r = 0; r < 4; ++r)
              op[(mt * 16 + 4 * g + r) * 64 + nh * 16 + f] = o[mt][nh][r];
      }

      if (bn < nb) {
#pragma unroll
        for (int mt = 0; mt < 2; ++mt)
#pragma unroll
          for (int ks = 0; ks < 2; ++ks) {
            xc[mt][ks][0] = xn[mt][ks][0];
            xc[mt][ks][1] = xn[mt][ks][1];
          }
      }
    }
  }
}

extern "C" void kernel_launch(void* const* d_in, const int* in_sizes, int n_in,
                              void* d_out, int out_size, void* d_ws, size_t ws_size,
                              hipStream_t stream) {
  const float* x = (const float*)d_in[0];
  const float* Wq = (const float*)d_in[1];
  const float* Wk = (const float*)d_in[2];
  const float* Wv = (const float*)d_in[3];
  const int nb = in_sizes[0] / 2048;  // batch blocks of 32x64
  float* out = (float*)d_out;
  float* attw = out + (size_t)nb * 2048;

  const int grid = 1024;  // 4096 waves, grid-stride over nb blocks
  lwmh_kernel<<<grid, 256, 0, stream>>>(x, Wq, Wk, Wv, out, attw, nb);
}

// Round 6
// 144.398 us; speedup vs baseline: 1.7898x; 1.7898x over previous
//
#include <hip/hip_runtime.h>
#include <math.h>

typedef float f32x4 __attribute__((ext_vector_type(4)));
typedef unsigned int u32x4 __attribute__((ext_vector_type(4)));
typedef short bf16x8 __attribute__((ext_vector_type(8)));

__device__ __forceinline__ unsigned f2bf1(float f) {
  unsigned u = __builtin_bit_cast(unsigned, f);
  return (u + 0x7FFFu + ((u >> 16) & 1u)) >> 16;
}
__device__ __forceinline__ unsigned pack2(float a, float b) {
  return f2bf1(a) | (f2bf1(b) << 16);
}

__device__ __forceinline__ f32x4 mfma16(u32x4 a, u32x4 b, f32x4 c) {
  return __builtin_amdgcn_mfma_f32_16x16x32_bf16(
      __builtin_bit_cast(bf16x8, a), __builtin_bit_cast(bf16x8, b), c, 0, 0, 0);
}

// LDS word-index swizzle: XOR row (word>>6) low bits into bits 2-4.
// Preserves 16B alignment; makes frag-pattern ds_write_b32 2-way (free).
__device__ __forceinline__ int swz(int word) {
  return word ^ (((word >> 6) & 7) << 2);
}

// Convert C/D accumulators of Z^T into A/B-layout bf16 fragments of Z.
template <int NS, int NF, int NKS>
__device__ __forceinline__ void cvt_frags(const f32x4 (&acc)[NS][NF],
                                          u32x4 (&frag)[NF][NKS],
                                          int f, int g) {
  unsigned pk[NS][NF][2];
#pragma unroll
  for (int s = 0; s < NS; ++s)
#pragma unroll
    for (int n = 0; n < NF; ++n) {
      pk[s][n][0] = pack2(acc[s][n][0], acc[s][n][1]);
      pk[s][n][1] = pack2(acc[s][n][2], acc[s][n][3]);
    }
  const bool hi = ((g >> 1) & 1) != 0;
#pragma unroll
  for (int w = 0; w < 4; ++w) {
    const int gp = 2 * (g & 1) + (w >> 1);
    const int idx = (f + (gp << 4)) << 2;
#pragma unroll
    for (int n = 0; n < NF; ++n)
#pragma unroll
      for (int ks = 0; ks < NKS; ++ks) {
        int lo = __builtin_amdgcn_ds_bpermute(idx, (int)pk[2 * ks + 0][n][w & 1]);
        int h2 = __builtin_amdgcn_ds_bpermute(idx, (int)pk[2 * ks + 1][n][w & 1]);
        frag[n][ks][w] = (unsigned)(hi ? h2 : lo);
      }
  }
}

__launch_bounds__(256, 2)
__global__ void lwmh_kernel(const float* __restrict__ x,
                            const float* __restrict__ Wq,
                            const float* __restrict__ Wk,
                            const float* __restrict__ Wv,
                            float* __restrict__ out,
                            float* __restrict__ attw,
                            int nb) {
  // 8KB per wave staging for the out block -> 1KB-contiguous store bursts.
  __shared__ float slds[4 * 2048];
  float* wl = slds + ((threadIdx.x >> 6) << 11);

  const int lane = threadIdx.x & 63;
  const int f = lane & 15;
  const int g = lane >> 4;
  const int wid = blockIdx.x * (blockDim.x >> 6) + (threadIdx.x >> 6);
  const int nwaves = gridDim.x * (blockDim.x >> 6);

  // ---- once-per-wave precompute ----
  u32x4 aWq[4][2], bWkT[4][2];
#pragma unroll
  for (int ct = 0; ct < 4; ++ct)
#pragma unroll
    for (int hs = 0; hs < 2; ++hs) {
      const int off = (ct * 16 + f) * 64 + hs * 32 + g * 8;
      f32x4 ql = *(const f32x4*)(Wq + off);
      f32x4 qh = *(const f32x4*)(Wq + off + 4);
      f32x4 kl = *(const f32x4*)(Wk + off);
      f32x4 kh = *(const f32x4*)(Wk + off + 4);
      u32x4 fq, fk;
      fq[0] = pack2(ql[0], ql[1]); fq[1] = pack2(ql[2], ql[3]);
      fq[2] = pack2(qh[0], qh[1]); fq[3] = pack2(qh[2], qh[3]);
      fk[0] = pack2(kl[0], kl[1]); fk[1] = pack2(kl[2], kl[3]);
      fk[2] = pack2(kh[0], kh[1]); fk[3] = pack2(kh[2], kh[3]);
      aWq[ct][hs] = fq;
      bWkT[ct][hs] = fk;
    }

  u32x4 wv[4][2];
#pragma unroll
  for (int t = 0; t < 4; ++t)
#pragma unroll
    for (int ks = 0; ks < 2; ++ks) {
      const float* bv = Wv + (ks * 32 + g * 8) * 64 + t * 16 + f;
      u32x4 fv;
#pragma unroll
      for (int w = 0; w < 4; ++w)
        fv[w] = pack2(bv[(2 * w) * 64], bv[(2 * w + 1) * 64]);
      wv[t][ks] = fv;
    }

  // N = Wk Wq^T / 8 as A-frags.
  u32x4 aN[4][2];
#pragma unroll
  for (int nc = 0; nc < 4; ++nc) {
    f32x4 nacc[4][1];
#pragma unroll
    for (int mc = 0; mc < 4; ++mc) {
      f32x4 a = {0.f, 0.f, 0.f, 0.f};
#pragma unroll
      for (int hs = 0; hs < 2; ++hs) a = mfma16(aWq[mc][hs], bWkT[nc][hs], a);
      nacc[mc][0] = a * 0.125f;
    }
    u32x4 tmp[1][2];
    cvt_frags<4, 1, 2>(nacc, tmp, f, g);
    aN[nc][0] = tmp[0][0];
    aN[nc][1] = tmp[0][1];
  }

  // ---- main grid-stride loop ----
  f32x4 xc[2][2][2], xn[2][2][2];

  auto loadX = [&](int b, f32x4 (&xr)[2][2][2]) {
    const float* xb = x + (size_t)b * 2048;
#pragma unroll
    for (int mt = 0; mt < 2; ++mt)
#pragma unroll
      for (int ks = 0; ks < 2; ++ks) {
        const float* p0 = xb + (mt * 16 + f) * 64 + ks * 32 + g * 8;
        xr[mt][ks][0] = *(const f32x4*)p0;
        xr[mt][ks][1] = *(const f32x4*)(p0 + 4);
      }
  };

  int b = wid;
  if (b < nb) loadX(b, xc);

  for (; b < nb; b += nwaves) {
    const int bn = b + nwaves;
    if (bn < nb) loadX(bn, xn);  // prefetch next block

    u32x4 xf[2][2];
#pragma unroll
    for (int mt = 0; mt < 2; ++mt)
#pragma unroll
      for (int ks = 0; ks < 2; ++ks) {
        u32x4 fr;
        fr[0] = pack2(xc[mt][ks][0][0], xc[mt][ks][0][1]);
        fr[1] = pack2(xc[mt][ks][0][2], xc[mt][ks][0][3]);
        fr[2] = pack2(xc[mt][ks][1][0], xc[mt][ks][1][1]);
        fr[3] = pack2(xc[mt][ks][1][2], xc[mt][ks][1][3]);
        xf[mt][ks] = fr;
      }

    // T2 = N @ X^T
    f32x4 t2[4][2];
#pragma unroll
    for (int mc = 0; mc < 4; ++mc)
#pragma unroll
      for (int nt = 0; nt < 2; ++nt) {
        f32x4 a = {0.f, 0.f, 0.f, 0.f};
#pragma unroll
        for (int ks = 0; ks < 2; ++ks) a = mfma16(aN[mc][ks], xf[nt][ks], a);
        t2[mc][nt] = a;
      }
    u32x4 bT2[2][2];
    cvt_frags<4, 2, 2>(t2, bT2, f, g);

    // V = X @ Wv
    f32x4 va[2][4];
#pragma unroll
    for (int ms = 0; ms < 2; ++ms)
#pragma unroll
      for (int nh = 0; nh < 4; ++nh) {
        f32x4 a = {0.f, 0.f, 0.f, 0.f};
#pragma unroll
        for (int ks = 0; ks < 2; ++ks) a = mfma16(xf[ms][ks], wv[nh][ks], a);
        va[ms][nh] = a;
      }
    u32x4 bV[4][1];
    cvt_frags<2, 4, 1>(va, bV, f, g);

    // S^T = X @ T2
    f32x4 st[2][2];
#pragma unroll
    for (int ms = 0; ms < 2; ++ms)
#pragma unroll
      for (int nt = 0; nt < 2; ++nt) {
        f32x4 a = {0.f, 0.f, 0.f, 0.f};
#pragma unroll
        for (int ks = 0; ks < 2; ++ks) a = mfma16(xf[ms][ks], bT2[nt][ks], a);
        st[ms][nt] = a;
      }

    // masked softmax over s
    f32x4 pe[2][2];
#pragma unroll
    for (int nt = 0; nt < 2; ++nt) {
      const int t = nt * 16 + f;
      float sum = 0.f;
#pragma unroll
      for (int ms = 0; ms < 2; ++ms)
#pragma unroll
        for (int r = 0; r < 4; ++r) {
          const int s = ms * 16 + 4 * g + r;
          const float e =
              ((unsigned)(t - s) <= 7u) ? __expf(st[ms][nt][r]) : 0.f;
          pe[ms][nt][r] = e;
          sum += e;
        }
      sum += __shfl_xor(sum, 16);
      sum += __shfl_xor(sum, 32);
      const float inv = 1.0f / sum;
#pragma unroll
      for (int ms = 0; ms < 2; ++ms)
        pe[ms][nt] *= inv;
    }

    // attention weights: direct f32x4 stores
    {
      float* aw = attw + (size_t)b * 1024;
#pragma unroll
      for (int ms = 0; ms < 2; ++ms)
#pragma unroll
        for (int nt = 0; nt < 2; ++nt)
          *(f32x4*)(aw + (nt * 16 + f) * 32 + ms * 16 + 4 * g) = pe[ms][nt];
    }

    // P -> bf16 A-frags
    u32x4 aP[2][1];
    cvt_frags<2, 2, 1>(pe, aP, f, g);

    // O = P @ V
    f32x4 o[2][4];
#pragma unroll
    for (int mt = 0; mt < 2; ++mt)
#pragma unroll
      for (int nh = 0; nh < 4; ++nh) {
        f32x4 a = {0.f, 0.f, 0.f, 0.f};
        o[mt][nh] = mfma16(aP[mt][0], bV[nh][0], a);
      }

    // O: stage in per-wave LDS slice (swizzled), dump as 8x 1KB-contiguous
    // global_store_dwordx4 bursts. No barrier: slice is wave-private;
    // compiler orders ds_write->ds_read via lgkmcnt.
    {
#pragma unroll
      for (int mt = 0; mt < 2; ++mt)
#pragma unroll
        for (int nh = 0; nh < 4; ++nh)
#pragma unroll
          for (int r = 0; r < 4; ++r) {
            const int word = (mt * 16 + 4 * g + r) * 64 + nh * 16 + f;
            wl[swz(word)] = o[mt][nh][r];
          }
      float* op = out + (size_t)b * 2048;
#pragma unroll
      for (int i = 0; i < 8; ++i) {
        const int word = i * 256 + lane * 4;
        const f32x4 vv = *(const f32x4*)(wl + swz(word));
        *(f32x4*)(op + word) = vv;
      }
    }

    // rotate prefetch buffer
    if (bn < nb) {
#pragma unroll
      for (int mt = 0; mt < 2; ++mt)
#pragma unroll
        for (int ks = 0; ks < 2; ++ks) {
          xc[mt][ks][0] = xn[mt][ks][0];
          xc[mt][ks][1] = xn[mt][ks][1];
        }
    }
  }
}

extern "C" void kernel_launch(void* const* d_in, const int* in_sizes, int n_in,
                              void* d_out, int out_size, void* d_ws, size_t ws_size,
                              hipStream_t stream) {
  const float* x = (const float*)d_in[0];
  const float* Wq = (const float*)d_in[1];
  const float* Wk = (const float*)d_in[2];
  const float* Wv = (const float*)d_in[3];
  const int nb = in_sizes[0] / 2048;  // batch blocks of 32x64
  float* out = (float*)d_out;
  float* attw = out + (size_t)nb * 2048;

  const int grid = 1024;  // 4096 waves, grid-stride over nb blocks
  lwmh_kernel<<<grid, 256, 0, stream>>>(x, Wq, Wk, Wv, out, attw, nb);
}